// Round 1
// baseline (3571.339 us; speedup 1.0000x reference)
//
#include <hip/hip_runtime.h>
#include <cstdint>
#include <cstddef>

#define BATCH   4
#define SEQ     8192
#define DREC    1024
#define CHUNK   64
#define NCHUNK  128              // SEQ/CHUNK
#define M_TOT   (BATCH*SEQ)      // 32768
#define N_AIV   3072

// ---------------------------------------------------------------------------
// Classic fp32 SGEMM: C[M,N] = A[M,K] @ B[K,N] (+bias broadcast over rows).
// 128x128 block tile, BK=8, 256 threads, 8x8 per thread.
// Requires M%128==0, N%128==0, K%8==0 (true for all our shapes).
// ---------------------------------------------------------------------------
__global__ __launch_bounds__(256) void sgemm_nn(
    const float* __restrict__ A, int lda,
    const float* __restrict__ B, int ldb,
    float* __restrict__ C, int ldc,
    int K, const float* __restrict__ bias)
{
    __shared__ float As[8][128];   // [k][m] (transposed A tile)
    __shared__ float Bs[8][128];   // [k][n]

    const int bm  = blockIdx.y * 128;
    const int bn  = blockIdx.x * 128;
    const int tid = threadIdx.x;
    const int tm  = (tid >> 4) << 3;   // (tid/16)*8
    const int tn  = (tid & 15) << 3;   // (tid%16)*8

    float acc[8][8];
    #pragma unroll
    for (int i = 0; i < 8; ++i)
        #pragma unroll
        for (int j = 0; j < 8; ++j) acc[i][j] = 0.f;

    const int ar_ = tid >> 1;          // 0..127 (A tile row)
    const int ac_ = (tid & 1) << 2;    // 0 or 4 (A tile col group)
    const int br_ = tid >> 5;          // 0..7   (B tile row)
    const int bc_ = (tid & 31) << 2;   // 0..124 (B tile col group)

    for (int k0 = 0; k0 < K; k0 += 8) {
        float4 av = *(const float4*)(A + (size_t)(bm + ar_) * lda + (k0 + ac_));
        float4 bv = *(const float4*)(B + (size_t)(k0 + br_) * ldb + (bn + bc_));
        As[ac_ + 0][ar_] = av.x;
        As[ac_ + 1][ar_] = av.y;
        As[ac_ + 2][ar_] = av.z;
        As[ac_ + 3][ar_] = av.w;
        *(float4*)(&Bs[br_][bc_]) = bv;
        __syncthreads();

        #pragma unroll
        for (int kk = 0; kk < 8; ++kk) {
            float arr[8], brr[8];
            *(float4*)&arr[0] = *(const float4*)&As[kk][tm];
            *(float4*)&arr[4] = *(const float4*)&As[kk][tm + 4];
            *(float4*)&brr[0] = *(const float4*)&Bs[kk][tn];
            *(float4*)&brr[4] = *(const float4*)&Bs[kk][tn + 4];
            #pragma unroll
            for (int i = 0; i < 8; ++i)
                #pragma unroll
                for (int j = 0; j < 8; ++j)
                    acc[i][j] = fmaf(arr[i], brr[j], acc[i][j]);
        }
        __syncthreads();
    }

    float bj[8];
    #pragma unroll
    for (int j = 0; j < 8; ++j) bj[j] = bias ? bias[bn + tn + j] : 0.f;
    #pragma unroll
    for (int i = 0; i < 8; ++i) {
        float* cp = C + (size_t)(bm + tm + i) * ldc + bn + tn;
        float4 v0 = make_float4(acc[i][0] + bj[0], acc[i][1] + bj[1],
                                acc[i][2] + bj[2], acc[i][3] + bj[3]);
        float4 v1 = make_float4(acc[i][4] + bj[4], acc[i][5] + bj[5],
                                acc[i][6] + bj[6], acc[i][7] + bj[7]);
        *(float4*)cp       = v0;
        *(float4*)(cp + 4) = v1;
    }
}

// ---------------------------------------------------------------------------
// Gates: aiv[m][0:1024]=a_proj, [1024:2048]=i_proj, [2048:3072]=v  (in place):
//   a      = sigmoid(a_proj + decay_bias)     -> slot 0
//   signal = sqrt(max(1-a*a,1e-8)) * (sigmoid(i_proj) * v) -> slot 1
// ---------------------------------------------------------------------------
__global__ __launch_bounds__(256) void fuse_gates(
    float* __restrict__ aiv, const float* __restrict__ decay_bias)
{
    size_t g = (size_t)blockIdx.x * 256 + threadIdx.x;   // < 32768*1024
    int    d = (int)(g & 1023);
    size_t m = g >> 10;
    size_t base = m * 3072 + (size_t)d;

    float ap = aiv[base];
    float ip = aiv[base + 1024];
    float vv = aiv[base + 2048];

    float a  = 1.f / (1.f + expf(-(ap + decay_bias[d])));
    float ii = 1.f / (1.f + expf(-ip));
    float sig = sqrtf(fmaxf(1.f - a * a, 1e-8f)) * (ii * vv);

    aiv[base]        = a;
    aiv[base + 1024] = sig;
}

// ---------------------------------------------------------------------------
// Intra-chunk pass (replicates reference fp32 numerics exactly, incl. the
// exp-underflow-to-0 behavior for fast channels):
//   cumlog += log(max(a,1e-10)); cd = exp(cumlog);
//   cw += signal / max(cd,1e-10); intra = cd*cw
// Writes: cd -> slot 0 (over a), intra -> slot 2 (over consumed v),
//         per-chunk summaries ctd/cfs at [b][chunk][d].
// One thread per (b,chunk,d): 524288 threads, 64 sequential steps.
// ---------------------------------------------------------------------------
__global__ __launch_bounds__(256) void scan_intra(
    float* __restrict__ aiv, float* __restrict__ ctd, float* __restrict__ cfs)
{
    size_t g  = (size_t)blockIdx.x * 256 + threadIdx.x;  // < 4*128*1024
    int    d  = (int)(g & 1023);
    int    bc = (int)(g >> 10);          // b*128 + chunk
    int    chunk = bc & (NCHUNK - 1);
    int    b     = bc >> 7;

    size_t row0 = ((size_t)b * SEQ + (size_t)chunk * CHUNK) * 3072 + (size_t)d;

    float cumlog = 0.f, cw = 0.f, cd = 0.f, intra = 0.f;
    for (int t = 0; t < CHUNK; ++t) {
        size_t idx = row0 + (size_t)t * 3072;
        float a = aiv[idx];
        float s = aiv[idx + 1024];
        cumlog += logf(fmaxf(a, 1e-10f));
        cd = expf(cumlog);
        cw += s / fmaxf(cd, 1e-10f);
        intra = cd * cw;
        aiv[idx + 2048] = intra;
        aiv[idx]        = cd;
    }
    size_t so = (size_t)bc * 1024 + (size_t)d;
    ctd[so] = cd;
    cfs[so] = intra;
}

// ---------------------------------------------------------------------------
// Inter-chunk scan: per (b,d), 128 chunk steps (reference fp32 numerics).
// incoming_state[n] = ccd[n-1]*cwc[n-1] for n>=1, 0 for n=0.
// ---------------------------------------------------------------------------
__global__ __launch_bounds__(256) void scan_inter(
    const float* __restrict__ ctd, const float* __restrict__ cfs,
    float* __restrict__ incoming)
{
    size_t g = (size_t)blockIdx.x * 256 + threadIdx.x;   // < 4*1024
    int    d = (int)(g & 1023);
    int    b = (int)(g >> 10);

    float cumlog = 0.f, cwc = 0.f;
    float pccd = 1.f, pcwc = 0.f;
    for (int n = 0; n < NCHUNK; ++n) {
        size_t o = ((size_t)b * NCHUNK + n) * 1024 + (size_t)d;
        incoming[o] = (n == 0) ? 0.f : pccd * pcwc;
        float t = ctd[o];
        cumlog += logf(fmaxf(t, 1e-10f));
        float ccd = expf(cumlog);
        cwc += cfs[o] / fmaxf(ccd, 1e-10f);
        pccd = ccd;
        pcwc = cwc;
    }
}

// ---------------------------------------------------------------------------
// Combine: h = intra + cd * incoming  -> slot 1 (over signal), ready as
// GEMM2 input with lda=3072.
// ---------------------------------------------------------------------------
__global__ __launch_bounds__(256) void combine(
    float* __restrict__ aiv, const float* __restrict__ incoming)
{
    size_t g = (size_t)blockIdx.x * 256 + threadIdx.x;   // < 32768*1024
    int    d = (int)(g & 1023);
    size_t m = g >> 10;                 // b*8192 + s
    int    s = (int)(m & (SEQ - 1));
    int    b = (int)(m >> 13);
    int    n = s >> 6;                  // chunk index

    size_t base = m * 3072 + (size_t)d;
    float cd    = aiv[base];
    float intra = aiv[base + 2048];
    float inc   = incoming[((size_t)b * NCHUNK + n) * 1024 + (size_t)d];
    aiv[base + 1024] = intra + cd * inc;
}

// ---------------------------------------------------------------------------
extern "C" void kernel_launch(void* const* d_in, const int* in_sizes, int n_in,
                              void* d_out, int out_size, void* d_ws, size_t ws_size,
                              hipStream_t stream)
{
    const float* x          = (const float*)d_in[0];  // (4,8192,1024)
    const float* W_aiv      = (const float*)d_in[1];  // (1024,3072)
    const float* decay_bias = (const float*)d_in[2];  // (1024,)
    const float* W_mix      = (const float*)d_in[3];  // (1024,1024)
    const float* b_mix      = (const float*)d_in[4];  // (1024,)
    float* out = (float*)d_out;                       // (4,8192,1024) fp32

    // Workspace layout (floats):
    //   aiv      : 32768*3072   (reused: a/signal -> cd/h/intra)
    //   ctd      : 4*128*1024
    //   cfs      : 4*128*1024
    //   incoming : 4*128*1024
    float* aiv      = (float*)d_ws;
    float* ctd      = aiv + (size_t)M_TOT * N_AIV;
    float* cfs      = ctd + (size_t)BATCH * NCHUNK * DREC;
    float* incoming = cfs + (size_t)BATCH * NCHUNK * DREC;

    // 1) aiv = x @ W_aiv
    {
        dim3 grid(N_AIV / 128, M_TOT / 128);
        sgemm_nn<<<grid, 256, 0, stream>>>(x, 1024, W_aiv, N_AIV, aiv, N_AIV,
                                           1024, nullptr);
    }
    // 2) gates (in place)
    fuse_gates<<<(M_TOT * DREC) / 256, 256, 0, stream>>>(aiv, decay_bias);
    // 3) intra-chunk scan
    scan_intra<<<(BATCH * NCHUNK * DREC) / 256, 256, 0, stream>>>(aiv, ctd, cfs);
    // 4) inter-chunk scan
    scan_inter<<<(BATCH * DREC) / 256, 256, 0, stream>>>(ctd, cfs, incoming);
    // 5) h = intra + cd*incoming
    combine<<<(M_TOT * DREC) / 256, 256, 0, stream>>>(aiv, incoming);
    // 6) out = h @ W_mix + b_mix
    {
        dim3 grid(DREC / 128, M_TOT / 128);
        sgemm_nn<<<grid, 256, 0, stream>>>(aiv + 1024, N_AIV, W_mix, DREC, out,
                                           DREC, 1024, b_mix);
    }
}

// Round 2
// 1453.187 us; speedup vs baseline: 2.4576x; 2.4576x over previous
//
#include <hip/hip_runtime.h>
#include <cstdint>
#include <cstddef>

#define BATCH   4
#define SEQ     8192
#define DREC    1024
#define CHUNK   64
#define NCHUNK  128              // SEQ/CHUNK
#define M_TOT   (BATCH*SEQ)      // 32768
#define N_AIV   3072

#define BM 128
#define BN 128
#define BK 32

typedef _Float16 half8  __attribute__((ext_vector_type(8)));
typedef float    floatx4 __attribute__((ext_vector_type(4)));

__device__ __forceinline__ void gl_lds16(const void* g, void* l) {
    __builtin_amdgcn_global_load_lds(
        (const __attribute__((address_space(1))) void*)g,
        (__attribute__((address_space(3))) void*)l, 16, 0, 0);
}

// ---------------------------------------------------------------------------
// C[M,N] = A_fp32[M,K] @ B[K,N] (+bias), via split-f16 MFMA (3 products):
//   A = Ahi + Alo (split in-kernel during staging), B pre-split+transposed
//   BT{hi,lo}[N,K] fp16, staged with global_load_lds (16B).
// 128x128 tile, BK=32, 256 threads (4 waves, each 64x64 = 4x4 frags of
// 16x16x32 f16 MFMA). LDS XOR-swizzle on the 16B k-group: slot q of row r
// holds global k-group (q ^ (r&3)).
// ---------------------------------------------------------------------------
__global__ __launch_bounds__(256) void gemm_split(
    const float* __restrict__ A, int lda,
    const _Float16* __restrict__ BThi, const _Float16* __restrict__ BTlo,
    float* __restrict__ C, int ldc, int K,
    const float* __restrict__ bias)
{
    __shared__ __align__(16) _Float16 sA[2][BM*BK];  // [hi/lo][r*32 + q*8 + e]
    __shared__ __align__(16) _Float16 sB[2][BN*BK];

    const int tid  = threadIdx.x;
    const int lane = tid & 63;
    const int wave = tid >> 6;
    const int bm = blockIdx.y * BM;
    const int bn = blockIdx.x * BN;
    const int wm = (wave >> 1) * 64;
    const int wn = (wave & 1) * 64;

    floatx4 acc[4][4];
    const floatx4 z4 = {0.f, 0.f, 0.f, 0.f};
    #pragma unroll
    for (int i = 0; i < 4; ++i)
        #pragma unroll
        for (int j = 0; j < 4; ++j) acc[i][j] = z4;

    // ---- A staging: thread t covers row ar = t>>1, q-slots {aq0, aq0+1}
    const int ar  = tid >> 1;
    const int aq0 = (tid & 1) * 2;
    const float* Arow = A + (size_t)(bm + ar) * lda;

    // ---- B staging (global_load_lds): LDS dst byte offset = tid*16 (+4096)
    const int bo0 = tid * 16, bo1 = bo0 + 4096;
    const int br0 = bo0 >> 6, bq0 = (bo0 >> 4) & 3;
    const int br1 = bo1 >> 6, bq1 = (bo1 >> 4) & 3;
    const int bg0 = (bq0 ^ (br0 & 3)) * 8;   // global k-element offset in tile
    const int bg1 = (bq1 ^ (br1 & 3)) * 8;
    const size_t bRow0 = (size_t)(bn + br0) * K;
    const size_t bRow1 = (size_t)(bn + br1) * K;

    // ---- fragment LDS offsets (elements), swizzle-corrected
    const int fm = lane & 15;
    const int fq = lane >> 4;
    int aoff[4], boff[4];
    #pragma unroll
    for (int i = 0; i < 4; ++i) {
        int m = wm + i * 16 + fm;
        aoff[i] = m * BK + ((fq ^ (m & 3)) << 3);
        int n = wn + i * 16 + fm;
        boff[i] = n * BK + ((fq ^ (n & 3)) << 3);
    }

    for (int k0 = 0; k0 < K; k0 += BK) {
        // B tiles: async global->LDS, 16B per lane
        gl_lds16(BThi + bRow0 + k0 + bg0, &sB[0][bo0 >> 1]);
        gl_lds16(BThi + bRow1 + k0 + bg1, &sB[0][bo1 >> 1]);
        gl_lds16(BTlo + bRow0 + k0 + bg0, &sB[1][bo0 >> 1]);
        gl_lds16(BTlo + bRow1 + k0 + bg1, &sB[1][bo1 >> 1]);

        // A tile: fp32 load -> split -> ds_write (hi & lo)
        #pragma unroll
        for (int qi = 0; qi < 2; ++qi) {
            int q  = aq0 + qi;
            int qg = q ^ (ar & 3);
            const float* src = Arow + k0 + qg * 8;
            float4 v0 = *(const float4*)src;
            float4 v1 = *(const float4*)(src + 4);
            float vv[8] = {v0.x, v0.y, v0.z, v0.w, v1.x, v1.y, v1.z, v1.w};
            half8 h, l;
            #pragma unroll
            for (int e = 0; e < 8; ++e) {
                _Float16 hi = (_Float16)vv[e];
                h[e] = hi;
                l[e] = (_Float16)(vv[e] - (float)hi);
            }
            *(half8*)&sA[0][ar * BK + q * 8] = h;
            *(half8*)&sA[1][ar * BK + q * 8] = l;
        }
        __syncthreads();

        half8 ah[4], al[4], bh[4], bl[4];
        #pragma unroll
        for (int i = 0; i < 4; ++i) {
            ah[i] = *(const half8*)&sA[0][aoff[i]];
            al[i] = *(const half8*)&sA[1][aoff[i]];
            bh[i] = *(const half8*)&sB[0][boff[i]];
            bl[i] = *(const half8*)&sB[1][boff[i]];
        }
        #pragma unroll
        for (int i = 0; i < 4; ++i)
            #pragma unroll
            for (int j = 0; j < 4; ++j) {
                acc[i][j] = __builtin_amdgcn_mfma_f32_16x16x32_f16(ah[i], bh[j], acc[i][j], 0, 0, 0);
                acc[i][j] = __builtin_amdgcn_mfma_f32_16x16x32_f16(ah[i], bl[j], acc[i][j], 0, 0, 0);
                acc[i][j] = __builtin_amdgcn_mfma_f32_16x16x32_f16(al[i], bh[j], acc[i][j], 0, 0, 0);
            }
        __syncthreads();
    }

    // epilogue: D[row][col], col = lane&15, row = (lane>>4)*4 + reg
    const int er = (lane >> 4) * 4;
    const int ec = lane & 15;
    #pragma unroll
    for (int j = 0; j < 4; ++j) {
        int col = bn + wn + j * 16 + ec;
        float bj = bias ? bias[col] : 0.f;
        #pragma unroll
        for (int i = 0; i < 4; ++i) {
            int rowb = bm + wm + i * 16 + er;
            #pragma unroll
            for (int r = 0; r < 4; ++r)
                C[(size_t)(rowb + r) * ldc + col] = acc[i][j][r] + bj;
        }
    }
}

// ---------------------------------------------------------------------------
// W[K,N] fp32 -> WT{hi,lo}[N,K] fp16 (transpose + split), 32x32 LDS tiles.
// ---------------------------------------------------------------------------
__global__ __launch_bounds__(256) void transpose_split(
    const float* __restrict__ W, int K, int N,
    _Float16* __restrict__ Thi, _Float16* __restrict__ Tlo)
{
    __shared__ float tile[32][33];
    const int k0 = blockIdx.y * 32, n0 = blockIdx.x * 32;
    const int tx = threadIdx.x & 31, ty = threadIdx.x >> 5;  // ty 0..7
    #pragma unroll
    for (int r = 0; r < 32; r += 8)
        tile[ty + r][tx] = W[(size_t)(k0 + ty + r) * N + n0 + tx];
    __syncthreads();
    #pragma unroll
    for (int r = 0; r < 32; r += 8) {
        float v = tile[tx][ty + r];
        _Float16 hi = (_Float16)v;
        size_t o = (size_t)(n0 + ty + r) * K + k0 + tx;
        Thi[o] = hi;
        Tlo[o] = (_Float16)(v - (float)hi);
    }
}

// ---------------------------------------------------------------------------
// Gates (float4-vectorized, in place on aiv):
//   a = sigmoid(a_proj + decay_bias) -> slot0
//   signal = sqrt(max(1-a*a,1e-8)) * sigmoid(i_proj)*v -> slot1
// ---------------------------------------------------------------------------
__global__ __launch_bounds__(256) void fuse_gates(
    float* __restrict__ aiv, const float* __restrict__ decay_bias)
{
    size_t g = (size_t)blockIdx.x * 256 + threadIdx.x;   // < 32768*256
    int    d4 = (int)(g & 255);
    size_t m  = g >> 8;
    size_t base = m * 3072 + (size_t)d4 * 4;

    float4 ap = *(const float4*)&aiv[base];
    float4 ip = *(const float4*)&aiv[base + 1024];
    float4 vv = *(const float4*)&aiv[base + 2048];
    float4 db = *(const float4*)&decay_bias[d4 * 4];

    float a[4] = {ap.x + db.x, ap.y + db.y, ap.z + db.z, ap.w + db.w};
    float ii[4] = {ip.x, ip.y, ip.z, ip.w};
    float vs[4] = {vv.x, vv.y, vv.z, vv.w};
    float ao[4], so[4];
    #pragma unroll
    for (int e = 0; e < 4; ++e) {
        float av = 1.f / (1.f + expf(-a[e]));
        float iv = 1.f / (1.f + expf(-ii[e]));
        ao[e] = av;
        so[e] = sqrtf(fmaxf(1.f - av * av, 1e-8f)) * (iv * vs[e]);
    }
    *(float4*)&aiv[base]        = make_float4(ao[0], ao[1], ao[2], ao[3]);
    *(float4*)&aiv[base + 1024] = make_float4(so[0], so[1], so[2], so[3]);
}

// ---------------------------------------------------------------------------
// Intra-chunk scan, float4 over d (reference fp32 numerics preserved).
// ---------------------------------------------------------------------------
__global__ __launch_bounds__(256) void scan_intra(
    float* __restrict__ aiv, float* __restrict__ ctd, float* __restrict__ cfs)
{
    int g  = blockIdx.x * 256 + threadIdx.x;  // < 4*128*256 = 131072
    int d4 = g & 255;
    int bc = g >> 8;                           // b*128 + chunk
    int chunk = bc & (NCHUNK - 1);
    int b     = bc >> 7;

    size_t row0 = ((size_t)b * SEQ + (size_t)chunk * CHUNK) * 3072 + (size_t)d4 * 4;

    float cl[4] = {0, 0, 0, 0}, cw[4] = {0, 0, 0, 0};
    float cd[4] = {0, 0, 0, 0}, in[4] = {0, 0, 0, 0};
    for (int t = 0; t < CHUNK; ++t) {
        size_t idx = row0 + (size_t)t * 3072;
        float4 av = *(const float4*)&aiv[idx];
        float4 sv = *(const float4*)&aiv[idx + 1024];
        float aa[4] = {av.x, av.y, av.z, av.w};
        float ss[4] = {sv.x, sv.y, sv.z, sv.w};
        #pragma unroll
        for (int e = 0; e < 4; ++e) {
            cl[e] += logf(fmaxf(aa[e], 1e-10f));
            cd[e] = expf(cl[e]);
            cw[e] += ss[e] / fmaxf(cd[e], 1e-10f);
            in[e] = cd[e] * cw[e];
        }
        *(float4*)&aiv[idx + 2048] = make_float4(in[0], in[1], in[2], in[3]);
        *(float4*)&aiv[idx]        = make_float4(cd[0], cd[1], cd[2], cd[3]);
    }
    size_t so = (size_t)bc * 1024 + (size_t)d4 * 4;
    *(float4*)&ctd[so] = make_float4(cd[0], cd[1], cd[2], cd[3]);
    *(float4*)&cfs[so] = make_float4(in[0], in[1], in[2], in[3]);
}

// ---------------------------------------------------------------------------
// Inter-chunk scan: per (b,d), 128 chunk steps (reference fp32 numerics).
// ---------------------------------------------------------------------------
__global__ __launch_bounds__(256) void scan_inter(
    const float* __restrict__ ctd, const float* __restrict__ cfs,
    float* __restrict__ incoming)
{
    int g = blockIdx.x * 256 + threadIdx.x;   // < 4*1024
    int d = g & 1023;
    int b = g >> 10;

    float cumlog = 0.f, cwc = 0.f;
    float pccd = 1.f, pcwc = 0.f;
    #pragma unroll 4
    for (int n = 0; n < NCHUNK; ++n) {
        size_t o = ((size_t)b * NCHUNK + n) * 1024 + (size_t)d;
        float t = ctd[o];
        float f = cfs[o];
        incoming[o] = (n == 0) ? 0.f : pccd * pcwc;
        cumlog += logf(fmaxf(t, 1e-10f));
        float ccd = expf(cumlog);
        cwc += f / fmaxf(ccd, 1e-10f);
        pccd = ccd;
        pcwc = cwc;
    }
}

// ---------------------------------------------------------------------------
// Combine: h = intra + cd*incoming -> slot1 (float4).
// ---------------------------------------------------------------------------
__global__ __launch_bounds__(256) void combine(
    float* __restrict__ aiv, const float* __restrict__ incoming)
{
    size_t g = (size_t)blockIdx.x * 256 + threadIdx.x;   // < 32768*256
    int    d4 = (int)(g & 255);
    size_t m  = g >> 8;
    int    s = (int)(m & (SEQ - 1));
    int    b = (int)(m >> 13);
    int    n = s >> 6;

    size_t base = m * 3072 + (size_t)d4 * 4;
    float4 cd    = *(const float4*)&aiv[base];
    float4 intra = *(const float4*)&aiv[base + 2048];
    float4 inc   = *(const float4*)&incoming[((size_t)b * NCHUNK + n) * 1024 + d4 * 4];
    float4 h = make_float4(intra.x + cd.x * inc.x, intra.y + cd.y * inc.y,
                           intra.z + cd.z * inc.z, intra.w + cd.w * inc.w);
    *(float4*)&aiv[base + 1024] = h;
}

// ---------------------------------------------------------------------------
extern "C" void kernel_launch(void* const* d_in, const int* in_sizes, int n_in,
                              void* d_out, int out_size, void* d_ws, size_t ws_size,
                              hipStream_t stream)
{
    const float* x          = (const float*)d_in[0];  // (4,8192,1024)
    const float* W_aiv      = (const float*)d_in[1];  // (1024,3072)
    const float* decay_bias = (const float*)d_in[2];  // (1024,)
    const float* W_mix      = (const float*)d_in[3];  // (1024,1024)
    const float* b_mix      = (const float*)d_in[4];  // (1024,)
    float* out = (float*)d_out;                       // (4,8192,1024) fp32

    // Workspace layout:
    //   aiv      fp32 M_TOT*3072                      (384 MB)
    //   ctd, cfs, incoming fp32 4*128*1024 each       (6 MB)
    //   wthi, wtlo fp16 3072*1024 each                (12 MB)
    //   mthi, mtlo fp16 1024*1024 each                (4 MB)
    float* aiv      = (float*)d_ws;
    float* ctd      = aiv + (size_t)M_TOT * N_AIV;
    float* cfs      = ctd + (size_t)BATCH * NCHUNK * DREC;
    float* incoming = cfs + (size_t)BATCH * NCHUNK * DREC;
    _Float16* wthi  = (_Float16*)(incoming + (size_t)BATCH * NCHUNK * DREC);
    _Float16* wtlo  = wthi + (size_t)N_AIV * DREC;
    _Float16* mthi  = wtlo + (size_t)N_AIV * DREC;
    _Float16* mtlo  = mthi + (size_t)DREC * DREC;

    // 0) weight transpose+split (cheap, every call: graph-safe & stateless)
    {
        dim3 g1(N_AIV / 32, DREC / 32);
        transpose_split<<<g1, 256, 0, stream>>>(W_aiv, DREC, N_AIV, wthi, wtlo);
        dim3 g2(DREC / 32, DREC / 32);
        transpose_split<<<g2, 256, 0, stream>>>(W_mix, DREC, DREC, mthi, mtlo);
    }
    // 1) aiv = x @ W_aiv   (MFMA split-f16)
    {
        dim3 grid(N_AIV / BN, M_TOT / BM);
        gemm_split<<<grid, 256, 0, stream>>>(x, DREC, wthi, wtlo,
                                             aiv, N_AIV, DREC, nullptr);
    }
    // 2) gates
    fuse_gates<<<(M_TOT * 256) / 256, 256, 0, stream>>>(aiv, decay_bias);
    // 3) intra-chunk scan
    scan_intra<<<(BATCH * NCHUNK * 256) / 256, 256, 0, stream>>>(aiv, ctd, cfs);
    // 4) inter-chunk scan
    scan_inter<<<(BATCH * DREC) / 256, 256, 0, stream>>>(ctd, cfs, incoming);
    // 5) h = intra + cd*incoming -> slot1
    combine<<<(M_TOT * 256) / 256, 256, 0, stream>>>(aiv, incoming);
    // 6) out = h @ W_mix + b_mix  (MFMA split-f16, strided A)
    {
        dim3 grid(DREC / BN, M_TOT / BM);
        gemm_split<<<grid, 256, 0, stream>>>(aiv + 1024, N_AIV, mthi, mtlo,
                                             out, DREC, DREC, b_mix);
    }
}

// Round 3
// 1101.606 us; speedup vs baseline: 3.2419x; 1.3192x over previous
//
#include <hip/hip_runtime.h>
#include <cstdint>
#include <cstddef>

#define BATCH   4
#define SEQ     8192
#define DREC    1024
#define CHUNK   64
#define NCHUNK  128              // SEQ/CHUNK
#define M_TOT   (BATCH*SEQ)      // 32768
#define N_AIV   3072

#define BM 128
#define BN 128
#define BK 32

typedef _Float16 half8 __attribute__((ext_vector_type(8)));
typedef float   floatx4 __attribute__((ext_vector_type(4)));

__device__ __forceinline__ void gl_lds16(const void* g, void* l) {
    __builtin_amdgcn_global_load_lds(
        (const __attribute__((address_space(1))) void*)g,
        (__attribute__((address_space(3))) void*)l, 16, 0, 0);
}

// ---------------------------------------------------------------------------
// C[M,N] = A_fp32[M,K] @ B[K,N] (+bias), pure-f16 MFMA (1 product):
//   A fp32, converted to f16 during LDS staging (VALU cvt + ds_write).
//   B pre-transposed+converted: BT[N,K] f16, staged with global_load_lds 16B.
// 128x128 tile, BK=32, 256 threads (4 waves, 64x64 each, 4x4 frags of
// 16x16x32 f16 MFMA). LDS swizzle: slot s (16B) of row r holds global
// k-group g = s ^ ((r>>1)&3)  -> conflict-free b128 frag reads.
// ---------------------------------------------------------------------------
__global__ __launch_bounds__(256) void gemm_f16(
    const float* __restrict__ A, int lda,
    const _Float16* __restrict__ BT, int ldb,
    float* __restrict__ C, int ldc, int K,
    const float* __restrict__ bias)
{
    __shared__ __align__(16) _Float16 sA[BM * BK];   // [r*32 + s*8 + e]
    __shared__ __align__(16) _Float16 sB[BN * BK];

    const int tid  = threadIdx.x;
    const int lane = tid & 63;
    const int wave = tid >> 6;
    const int bm = blockIdx.y * BM;
    const int bn = blockIdx.x * BN;
    const int wm = (wave >> 1) * 64;
    const int wn = (wave & 1) * 64;

    floatx4 acc[4][4];
    const floatx4 z4 = {0.f, 0.f, 0.f, 0.f};
    #pragma unroll
    for (int i = 0; i < 4; ++i)
        #pragma unroll
        for (int j = 0; j < 4; ++j) acc[i][j] = z4;

    // ---- A staging: thread t -> row ar = t>>1, slots {as0, as0+1}
    const int ar  = tid >> 1;
    const int as0 = (tid & 1) * 2;
    const float* Arow = A + (size_t)(bm + ar) * lda;
    const int ag0 = ((as0 + 0) ^ ((ar >> 1) & 3)) * 8;  // global k-elem offset
    const int ag1 = ((as0 + 1) ^ ((ar >> 1) & 3)) * 8;

    // ---- B staging (global_load_lds): 2 calls, LDS byte off = c*4096 + tid*16
    const int bo0 = tid * 16, bo1 = bo0 + 4096;
    const int br0 = bo0 >> 6, bs0 = (bo0 >> 4) & 3;
    const int br1 = bo1 >> 6, bs1 = (bo1 >> 4) & 3;
    const int bg0 = (bs0 ^ ((br0 >> 1) & 3)) * 8;
    const int bg1 = (bs1 ^ ((br1 >> 1) & 3)) * 8;
    const size_t bRow0 = (size_t)(bn + br0) * ldb;
    const size_t bRow1 = (size_t)(bn + br1) * ldb;

    // ---- fragment LDS offsets (f16 elements), swizzle-corrected
    const int fm = lane & 15;
    const int fq = lane >> 4;
    int aoff[4], boff[4];
    #pragma unroll
    for (int i = 0; i < 4; ++i) {
        int m = wm + i * 16 + fm;
        aoff[i] = m * BK + ((fq ^ ((m >> 1) & 3)) << 3);
        int n = wn + i * 16 + fm;
        boff[i] = n * BK + ((fq ^ ((n >> 1) & 3)) << 3);
    }

    for (int k0 = 0; k0 < K; k0 += BK) {
        // B tile: async global->LDS
        gl_lds16(BT + bRow0 + k0 + bg0, (char*)sB + bo0);
        gl_lds16(BT + bRow1 + k0 + bg1, (char*)sB + bo1);

        // A tile: fp32 load -> cvt f16 -> ds_write_b128
        {
            const float* s0 = Arow + k0 + ag0;
            const float* s1 = Arow + k0 + ag1;
            float4 a0 = *(const float4*)s0;
            float4 a1 = *(const float4*)(s0 + 4);
            float4 b0 = *(const float4*)s1;
            float4 b1 = *(const float4*)(s1 + 4);
            half8 h0, h1;
            h0[0] = (_Float16)a0.x; h0[1] = (_Float16)a0.y;
            h0[2] = (_Float16)a0.z; h0[3] = (_Float16)a0.w;
            h0[4] = (_Float16)a1.x; h0[5] = (_Float16)a1.y;
            h0[6] = (_Float16)a1.z; h0[7] = (_Float16)a1.w;
            h1[0] = (_Float16)b0.x; h1[1] = (_Float16)b0.y;
            h1[2] = (_Float16)b0.z; h1[3] = (_Float16)b0.w;
            h1[4] = (_Float16)b1.x; h1[5] = (_Float16)b1.y;
            h1[6] = (_Float16)b1.z; h1[7] = (_Float16)b1.w;
            *(half8*)&sA[ar * BK + (as0 + 0) * 8] = h0;
            *(half8*)&sA[ar * BK + (as0 + 1) * 8] = h1;
        }
        __syncthreads();

        half8 ah[4], bh[4];
        #pragma unroll
        for (int i = 0; i < 4; ++i) {
            ah[i] = *(const half8*)&sA[aoff[i]];
            bh[i] = *(const half8*)&sB[boff[i]];
        }
        #pragma unroll
        for (int i = 0; i < 4; ++i)
            #pragma unroll
            for (int j = 0; j < 4; ++j)
                acc[i][j] = __builtin_amdgcn_mfma_f32_16x16x32_f16(
                    ah[i], bh[j], acc[i][j], 0, 0, 0);
        __syncthreads();
    }

    // epilogue: D[row][col], col = lane&15, row = (lane>>4)*4 + reg
    const int er = (lane >> 4) * 4;
    const int ec = lane & 15;
    #pragma unroll
    for (int j = 0; j < 4; ++j) {
        int col = bn + wn + j * 16 + ec;
        float bj = bias ? bias[col] : 0.f;
        #pragma unroll
        for (int i = 0; i < 4; ++i) {
            int rowb = bm + wm + i * 16 + er;
            #pragma unroll
            for (int r = 0; r < 4; ++r)
                C[(size_t)(rowb + r) * ldc + col] = acc[i][j][r] + bj;
        }
    }
}

// ---------------------------------------------------------------------------
// W[K,N] fp32 -> T[N,K] f16 (transpose + convert), 32x32 LDS tiles.
// ---------------------------------------------------------------------------
__global__ __launch_bounds__(256) void transpose_cvt(
    const float* __restrict__ W, int K, int N, _Float16* __restrict__ T)
{
    __shared__ float tile[32][33];
    const int k0 = blockIdx.y * 32, n0 = blockIdx.x * 32;
    const int tx = threadIdx.x & 31, ty = threadIdx.x >> 5;  // ty 0..7
    #pragma unroll
    for (int r = 0; r < 32; r += 8)
        tile[ty + r][tx] = W[(size_t)(k0 + ty + r) * N + n0 + tx];
    __syncthreads();
    #pragma unroll
    for (int r = 0; r < 32; r += 8)
        T[(size_t)(n0 + ty + r) * K + k0 + tx] = (_Float16)tile[tx][ty + r];
}

// ---------------------------------------------------------------------------
// Pass A (fused gates + intra scan, summaries only):
// reads aiv (a_proj/i_proj/v), computes a/signal inline, runs the 64-step
// reference-numerics scan, writes per-chunk ctd (total decay) and cfs
// (final state) only. One thread per (b,chunk,d4): float4 over d.
// ---------------------------------------------------------------------------
__global__ __launch_bounds__(256) void scan_chunks(
    const float* __restrict__ aiv, const float* __restrict__ decay_bias,
    float* __restrict__ ctd, float* __restrict__ cfs)
{
    int g  = blockIdx.x * 256 + threadIdx.x;   // < 4*128*256
    int d4 = g & 255;
    int bc = g >> 8;                            // b*128 + chunk
    int chunk = bc & (NCHUNK - 1);
    int b     = bc >> 7;

    size_t row0 = ((size_t)b * SEQ + (size_t)chunk * CHUNK) * 3072 + (size_t)d4 * 4;
    float4 db4 = *(const float4*)&decay_bias[d4 * 4];
    float db[4] = {db4.x, db4.y, db4.z, db4.w};

    float cl[4] = {0, 0, 0, 0}, cw[4] = {0, 0, 0, 0}, cd[4] = {0, 0, 0, 0};
    for (int t = 0; t < CHUNK; ++t) {
        size_t idx = row0 + (size_t)t * 3072;
        float4 ap = *(const float4*)&aiv[idx];
        float4 ip = *(const float4*)&aiv[idx + 1024];
        float4 vv = *(const float4*)&aiv[idx + 2048];
        float apv[4] = {ap.x, ap.y, ap.z, ap.w};
        float ipv[4] = {ip.x, ip.y, ip.z, ip.w};
        float vvv[4] = {vv.x, vv.y, vv.z, vv.w};
        #pragma unroll
        for (int e = 0; e < 4; ++e) {
            float a  = 1.f / (1.f + expf(-(apv[e] + db[e])));
            float ii = 1.f / (1.f + expf(-ipv[e]));
            float s  = sqrtf(fmaxf(1.f - a * a, 1e-8f)) * (ii * vvv[e]);
            cl[e] += logf(fmaxf(a, 1e-10f));
            cd[e] = expf(cl[e]);
            cw[e] += s / fmaxf(cd[e], 1e-10f);
        }
    }
    size_t so = (size_t)bc * 1024 + (size_t)d4 * 4;
    *(float4*)&ctd[so] = make_float4(cd[0], cd[1], cd[2], cd[3]);
    *(float4*)&cfs[so] = make_float4(cd[0] * cw[0], cd[1] * cw[1],
                                     cd[2] * cw[2], cd[3] * cw[3]);
}

// ---------------------------------------------------------------------------
// Inter-chunk scan: per (b,d), 128 chunk steps (reference fp32 numerics).
// ---------------------------------------------------------------------------
__global__ __launch_bounds__(256) void scan_inter(
    const float* __restrict__ ctd, const float* __restrict__ cfs,
    float* __restrict__ incoming)
{
    int g = blockIdx.x * 256 + threadIdx.x;   // < 4*1024
    int d = g & 1023;
    int b = g >> 10;

    float cumlog = 0.f, cwc = 0.f;
    float pccd = 1.f, pcwc = 0.f;
    #pragma unroll 4
    for (int n = 0; n < NCHUNK; ++n) {
        size_t o = ((size_t)b * NCHUNK + n) * 1024 + (size_t)d;
        float t = ctd[o];
        float f = cfs[o];
        incoming[o] = (n == 0) ? 0.f : pccd * pcwc;
        cumlog += logf(fmaxf(t, 1e-10f));
        float ccd = expf(cumlog);
        cwc += f / fmaxf(ccd, 1e-10f);
        pccd = ccd;
        pcwc = cwc;
    }
}

// ---------------------------------------------------------------------------
// Pass C (fused gates + intra scan + combine): recomputes the identical
// intra scan, adds cd*incoming, writes h fp32 IN PLACE over the v slot
// (exact per-thread footprint: read v float4 -> write h float4, no
// cross-thread aliasing).
// ---------------------------------------------------------------------------
__global__ __launch_bounds__(256) void scan_apply(
    float* __restrict__ aiv, const float* __restrict__ decay_bias,
    const float* __restrict__ incoming)
{
    int g  = blockIdx.x * 256 + threadIdx.x;   // < 4*128*256
    int d4 = g & 255;
    int bc = g >> 8;
    int chunk = bc & (NCHUNK - 1);
    int b     = bc >> 7;

    size_t row0 = ((size_t)b * SEQ + (size_t)chunk * CHUNK) * 3072 + (size_t)d4 * 4;
    float4 db4 = *(const float4*)&decay_bias[d4 * 4];
    float db[4] = {db4.x, db4.y, db4.z, db4.w};
    float4 ic4 = *(const float4*)&incoming[((size_t)b * NCHUNK + chunk) * 1024 + d4 * 4];
    float inc[4] = {ic4.x, ic4.y, ic4.z, ic4.w};

    float cl[4] = {0, 0, 0, 0}, cw[4] = {0, 0, 0, 0};
    for (int t = 0; t < CHUNK; ++t) {
        size_t idx = row0 + (size_t)t * 3072;
        float4 ap = *(const float4*)&aiv[idx];
        float4 ip = *(const float4*)&aiv[idx + 1024];
        float4 vv = *(const float4*)&aiv[idx + 2048];
        float apv[4] = {ap.x, ap.y, ap.z, ap.w};
        float ipv[4] = {ip.x, ip.y, ip.z, ip.w};
        float vvv[4] = {vv.x, vv.y, vv.z, vv.w};
        float h[4];
        #pragma unroll
        for (int e = 0; e < 4; ++e) {
            float a  = 1.f / (1.f + expf(-(apv[e] + db[e])));
            float ii = 1.f / (1.f + expf(-ipv[e]));
            float s  = sqrtf(fmaxf(1.f - a * a, 1e-8f)) * (ii * vvv[e]);
            cl[e] += logf(fmaxf(a, 1e-10f));
            float cd = expf(cl[e]);
            cw[e] += s / fmaxf(cd, 1e-10f);
            h[e] = cd * cw[e] + cd * inc[e];
        }
        *(float4*)&aiv[idx + 2048] = make_float4(h[0], h[1], h[2], h[3]);
    }
}

// ---------------------------------------------------------------------------
extern "C" void kernel_launch(void* const* d_in, const int* in_sizes, int n_in,
                              void* d_out, int out_size, void* d_ws, size_t ws_size,
                              hipStream_t stream)
{
    const float* x          = (const float*)d_in[0];  // (4,8192,1024)
    const float* W_aiv      = (const float*)d_in[1];  // (1024,3072)
    const float* decay_bias = (const float*)d_in[2];  // (1024,)
    const float* W_mix      = (const float*)d_in[3];  // (1024,1024)
    const float* b_mix      = (const float*)d_in[4];  // (1024,)
    float* out = (float*)d_out;                       // (4,8192,1024) fp32

    // Workspace (417 MB total, <= proven 426 MB):
    float* aiv      = (float*)d_ws;                          // 32768*3072 f32
    float* ctd      = aiv + (size_t)M_TOT * N_AIV;           // 4*128*1024
    float* cfs      = ctd + (size_t)BATCH * NCHUNK * DREC;
    float* incoming = cfs + (size_t)BATCH * NCHUNK * DREC;
    _Float16* wT    = (_Float16*)(incoming + (size_t)BATCH * NCHUNK * DREC); // [3072,1024]
    _Float16* mT    = wT + (size_t)N_AIV * DREC;                             // [1024,1024]

    // 0) weight transpose+convert (tiny)
    {
        dim3 g1(N_AIV / 32, DREC / 32);
        transpose_cvt<<<g1, 256, 0, stream>>>(W_aiv, DREC, N_AIV, wT);
        dim3 g2(DREC / 32, DREC / 32);
        transpose_cvt<<<g2, 256, 0, stream>>>(W_mix, DREC, DREC, mT);
    }
    // 1) aiv = x @ W_aiv   (pure-f16 MFMA)
    {
        dim3 grid(N_AIV / BN, M_TOT / BM);
        gemm_f16<<<grid, 256, 0, stream>>>(x, DREC, wT, DREC,
                                           aiv, N_AIV, DREC, nullptr);
    }
    // 2) fused gates + intra scan -> chunk summaries
    scan_chunks<<<(BATCH * NCHUNK * 256) / 256, 256, 0, stream>>>(
        aiv, decay_bias, ctd, cfs);
    // 3) inter-chunk scan
    scan_inter<<<(BATCH * DREC) / 256, 256, 0, stream>>>(ctd, cfs, incoming);
    // 4) fused gates + intra scan + combine -> h (in place over v slot)
    scan_apply<<<(BATCH * NCHUNK * 256) / 256, 256, 0, stream>>>(
        aiv, decay_bias, incoming);
    // 5) out = h @ W_mix + b_mix  (pure-f16 MFMA, strided A)
    {
        dim3 grid(DREC / BN, M_TOT / BM);
        gemm_f16<<<grid, 256, 0, stream>>>(aiv + 2048, N_AIV, mT, DREC,
                                           out, DREC, DREC, b_mix);
    }
}

// Round 4
// 895.450 us; speedup vs baseline: 3.9883x; 1.2302x over previous
//
#include <hip/hip_runtime.h>
#include <cstdint>
#include <cstddef>

#define BATCH   4
#define SEQ     8192
#define DREC    1024
#define CHUNK   64
#define NCHUNK  128              // SEQ/CHUNK
#define M_TOT   (BATCH*SEQ)      // 32768
#define N_AIV   3072

#define BM 128
#define BN 128
#define BK 32

typedef _Float16 half8 __attribute__((ext_vector_type(8)));
typedef _Float16 half4 __attribute__((ext_vector_type(4)));
typedef float   floatx4 __attribute__((ext_vector_type(4)));

__device__ __forceinline__ void gl_lds16(const void* g, void* l) {
    __builtin_amdgcn_global_load_lds(
        (const __attribute__((address_space(1))) void*)g,
        (__attribute__((address_space(3))) void*)l, 16, 0, 0);
}

// ---------------------------------------------------------------------------
// C[M,N] = A_f16[M,K] @ B[K,N] (+bias), pure-f16 MFMA, m97 structure:
// both A[M,K] and BT[N,K] f16 row-major, staged with global_load_lds 16B
// (2 calls each per K-iter). 128x128 tile, BK=32, 256 threads (4 waves,
// 64x64 each, 4x4 frags of 16x16x32 f16 MFMA).
// LDS swizzle: 16B slot s of row r holds global k-group g = s ^ ((r>>1)&3).
// F16_OUT: write C as f16 (GEMM1 -> aivh), else fp32 (+bias) (GEMM2 -> out).
// ---------------------------------------------------------------------------
template <bool F16_OUT>
__global__ __launch_bounds__(256) void gemm_ff(
    const _Float16* __restrict__ A, int lda,
    const _Float16* __restrict__ BT, int ldb,
    void* __restrict__ Cv, int ldc, int K,
    const float* __restrict__ bias)
{
    __shared__ __align__(16) _Float16 sA[BM * BK];   // [r*32 + s*8 + e]
    __shared__ __align__(16) _Float16 sB[BN * BK];

    const int tid  = threadIdx.x;
    const int lane = tid & 63;
    const int wave = tid >> 6;
    const int bm = blockIdx.y * BM;
    const int bn = blockIdx.x * BN;
    const int wm = (wave >> 1) * 64;
    const int wn = (wave & 1) * 64;

    floatx4 acc[4][4];
    const floatx4 z4 = {0.f, 0.f, 0.f, 0.f};
    #pragma unroll
    for (int i = 0; i < 4; ++i)
        #pragma unroll
        for (int j = 0; j < 4; ++j) acc[i][j] = z4;

    // staging geometry (identical for A and B): byte offsets o0 = tid*16,
    // o1 = o0 + 4096; row = o>>6 (64 B/row), slot = (o>>4)&3,
    // global k-elem offset g = (slot ^ ((row>>1)&3))*8
    const int o0 = tid * 16, o1 = o0 + 4096;
    const int r0 = o0 >> 6, s0 = (o0 >> 4) & 3;
    const int r1 = o1 >> 6, s1 = (o1 >> 4) & 3;
    const int g0 = (s0 ^ ((r0 >> 1) & 3)) * 8;
    const int g1 = (s1 ^ ((r1 >> 1) & 3)) * 8;
    const size_t aRow0 = (size_t)(bm + r0) * lda;
    const size_t aRow1 = (size_t)(bm + r1) * lda;
    const size_t bRow0 = (size_t)(bn + r0) * ldb;
    const size_t bRow1 = (size_t)(bn + r1) * ldb;

    // fragment LDS offsets (f16 elements), swizzle-corrected
    const int fm = lane & 15;
    const int fq = lane >> 4;
    int aoff[4], boff[4];
    #pragma unroll
    for (int i = 0; i < 4; ++i) {
        int m = wm + i * 16 + fm;
        aoff[i] = m * BK + ((fq ^ ((m >> 1) & 3)) << 3);
        int n = wn + i * 16 + fm;
        boff[i] = n * BK + ((fq ^ ((n >> 1) & 3)) << 3);
    }

    for (int k0 = 0; k0 < K; k0 += BK) {
        gl_lds16(A  + aRow0 + k0 + g0, (char*)sA + o0);
        gl_lds16(A  + aRow1 + k0 + g1, (char*)sA + o1);
        gl_lds16(BT + bRow0 + k0 + g0, (char*)sB + o0);
        gl_lds16(BT + bRow1 + k0 + g1, (char*)sB + o1);
        __syncthreads();

        half8 ah[4], bh[4];
        #pragma unroll
        for (int i = 0; i < 4; ++i) {
            ah[i] = *(const half8*)&sA[aoff[i]];
            bh[i] = *(const half8*)&sB[boff[i]];
        }
        #pragma unroll
        for (int i = 0; i < 4; ++i)
            #pragma unroll
            for (int j = 0; j < 4; ++j)
                acc[i][j] = __builtin_amdgcn_mfma_f32_16x16x32_f16(
                    ah[i], bh[j], acc[i][j], 0, 0, 0);
        __syncthreads();
    }

    // epilogue: D[row][col], col = lane&15, row = (lane>>4)*4 + reg
    const int er = (lane >> 4) * 4;
    const int ec = lane & 15;
    #pragma unroll
    for (int j = 0; j < 4; ++j) {
        int col = bn + wn + j * 16 + ec;
        float bj = (!F16_OUT && bias) ? bias[col] : 0.f;
        #pragma unroll
        for (int i = 0; i < 4; ++i) {
            int rowb = bm + wm + i * 16 + er;
            #pragma unroll
            for (int r = 0; r < 4; ++r) {
                if (F16_OUT)
                    ((_Float16*)Cv)[(size_t)(rowb + r) * ldc + col] =
                        (_Float16)acc[i][j][r];
                else
                    ((float*)Cv)[(size_t)(rowb + r) * ldc + col] =
                        acc[i][j][r] + bj;
            }
        }
    }
}

// ---------------------------------------------------------------------------
// x fp32 -> f16, 8 elems/thread.
// ---------------------------------------------------------------------------
__global__ __launch_bounds__(256) void cvt_to_f16(
    const float* __restrict__ src, _Float16* __restrict__ dst)
{
    size_t i = ((size_t)blockIdx.x * 256 + threadIdx.x) * 8;
    float4 a = *(const float4*)(src + i);
    float4 b = *(const float4*)(src + i + 4);
    half8 h;
    h[0] = (_Float16)a.x; h[1] = (_Float16)a.y;
    h[2] = (_Float16)a.z; h[3] = (_Float16)a.w;
    h[4] = (_Float16)b.x; h[5] = (_Float16)b.y;
    h[6] = (_Float16)b.z; h[7] = (_Float16)b.w;
    *(half8*)(dst + i) = h;
}

// ---------------------------------------------------------------------------
// W[K,N] fp32 -> T[N,K] f16 (transpose + convert), 32x32 LDS tiles.
// ---------------------------------------------------------------------------
__global__ __launch_bounds__(256) void transpose_cvt(
    const float* __restrict__ W, int K, int N, _Float16* __restrict__ T)
{
    __shared__ float tile[32][33];
    const int k0 = blockIdx.y * 32, n0 = blockIdx.x * 32;
    const int tx = threadIdx.x & 31, ty = threadIdx.x >> 5;  // ty 0..7
    #pragma unroll
    for (int r = 0; r < 32; r += 8)
        tile[ty + r][tx] = W[(size_t)(k0 + ty + r) * N + n0 + tx];
    __syncthreads();
    #pragma unroll
    for (int r = 0; r < 32; r += 8)
        T[(size_t)(n0 + ty + r) * K + k0 + tx] = (_Float16)tile[tx][ty + r];
}

// ---------------------------------------------------------------------------
// Pass A (fused gates + intra scan, summaries only): reads aivh (f16),
// fp32 math identical to reference ordering, writes per-chunk ctd/cfs.
// One thread per (b,chunk,d4), 4 channels each.
// ---------------------------------------------------------------------------
__global__ __launch_bounds__(256) void scan_chunks(
    const _Float16* __restrict__ aivh, const float* __restrict__ decay_bias,
    float* __restrict__ ctd, float* __restrict__ cfs)
{
    int g  = blockIdx.x * 256 + threadIdx.x;   // < 4*128*256
    int d4 = g & 255;
    int bc = g >> 8;                            // b*128 + chunk
    int chunk = bc & (NCHUNK - 1);
    int b     = bc >> 7;

    size_t row0 = ((size_t)b * SEQ + (size_t)chunk * CHUNK) * 3072 + (size_t)d4 * 4;
    float4 db4 = *(const float4*)&decay_bias[d4 * 4];
    float db[4] = {db4.x, db4.y, db4.z, db4.w};

    float cl[4] = {0, 0, 0, 0}, cw[4] = {0, 0, 0, 0}, cd[4] = {0, 0, 0, 0};
    for (int t = 0; t < CHUNK; ++t) {
        size_t idx = row0 + (size_t)t * 3072;
        half4 ap = *(const half4*)&aivh[idx];
        half4 ip = *(const half4*)&aivh[idx + 1024];
        half4 vv = *(const half4*)&aivh[idx + 2048];
        #pragma unroll
        for (int e = 0; e < 4; ++e) {
            float a  = 1.f / (1.f + expf(-((float)ap[e] + db[e])));
            float ii = 1.f / (1.f + expf(-(float)ip[e]));
            float s  = sqrtf(fmaxf(1.f - a * a, 1e-8f)) * (ii * (float)vv[e]);
            cl[e] += logf(fmaxf(a, 1e-10f));
            cd[e] = expf(cl[e]);
            cw[e] += s / fmaxf(cd[e], 1e-10f);
        }
    }
    size_t so = (size_t)bc * 1024 + (size_t)d4 * 4;
    *(float4*)&ctd[so] = make_float4(cd[0], cd[1], cd[2], cd[3]);
    *(float4*)&cfs[so] = make_float4(cd[0] * cw[0], cd[1] * cw[1],
                                     cd[2] * cw[2], cd[3] * cw[3]);
}

// ---------------------------------------------------------------------------
// Inter-chunk scan: per (b,d), 128 chunk steps (reference fp32 numerics).
// ---------------------------------------------------------------------------
__global__ __launch_bounds__(256) void scan_inter(
    const float* __restrict__ ctd, const float* __restrict__ cfs,
    float* __restrict__ incoming)
{
    int g = blockIdx.x * 256 + threadIdx.x;   // < 4*1024
    int d = g & 1023;
    int b = g >> 10;

    float cumlog = 0.f, cwc = 0.f;
    float pccd = 1.f, pcwc = 0.f;
    #pragma unroll 4
    for (int n = 0; n < NCHUNK; ++n) {
        size_t o = ((size_t)b * NCHUNK + n) * 1024 + (size_t)d;
        float t = ctd[o];
        float f = cfs[o];
        incoming[o] = (n == 0) ? 0.f : pccd * pcwc;
        cumlog += logf(fmaxf(t, 1e-10f));
        float ccd = expf(cumlog);
        cwc += f / fmaxf(ccd, 1e-10f);
        pccd = ccd;
        pcwc = cwc;
    }
}

// ---------------------------------------------------------------------------
// Pass C (fused gates + intra scan + combine): recomputes the intra scan,
// adds cd*incoming, writes h as f16 into compact hb[M_TOT,1024].
// ---------------------------------------------------------------------------
__global__ __launch_bounds__(256) void scan_apply(
    const _Float16* __restrict__ aivh, const float* __restrict__ decay_bias,
    const float* __restrict__ incoming, _Float16* __restrict__ hb)
{
    int g  = blockIdx.x * 256 + threadIdx.x;   // < 4*128*256
    int d4 = g & 255;
    int bc = g >> 8;
    int chunk = bc & (NCHUNK - 1);
    int b     = bc >> 7;

    size_t row0  = ((size_t)b * SEQ + (size_t)chunk * CHUNK) * 3072 + (size_t)d4 * 4;
    size_t hrow0 = ((size_t)b * SEQ + (size_t)chunk * CHUNK) * 1024 + (size_t)d4 * 4;
    float4 db4 = *(const float4*)&decay_bias[d4 * 4];
    float db[4] = {db4.x, db4.y, db4.z, db4.w};
    float4 ic4 = *(const float4*)&incoming[((size_t)b * NCHUNK + chunk) * 1024 + d4 * 4];
    float inc[4] = {ic4.x, ic4.y, ic4.z, ic4.w};

    float cl[4] = {0, 0, 0, 0}, cw[4] = {0, 0, 0, 0};
    for (int t = 0; t < CHUNK; ++t) {
        size_t idx = row0 + (size_t)t * 3072;
        half4 ap = *(const half4*)&aivh[idx];
        half4 ip = *(const half4*)&aivh[idx + 1024];
        half4 vv = *(const half4*)&aivh[idx + 2048];
        half4 h;
        #pragma unroll
        for (int e = 0; e < 4; ++e) {
            float a  = 1.f / (1.f + expf(-((float)ap[e] + db[e])));
            float ii = 1.f / (1.f + expf(-(float)ip[e]));
            float s  = sqrtf(fmaxf(1.f - a * a, 1e-8f)) * (ii * (float)vv[e]);
            cl[e] += logf(fmaxf(a, 1e-10f));
            float cd = expf(cl[e]);
            cw[e] += s / fmaxf(cd, 1e-10f);
            h[e] = (_Float16)(cd * cw[e] + cd * inc[e]);
        }
        *(half4*)&hb[hrow0 + (size_t)t * 1024] = h;
    }
}

// ---------------------------------------------------------------------------
extern "C" void kernel_launch(void* const* d_in, const int* in_sizes, int n_in,
                              void* d_out, int out_size, void* d_ws, size_t ws_size,
                              hipStream_t stream)
{
    const float* x          = (const float*)d_in[0];  // (4,8192,1024)
    const float* W_aiv      = (const float*)d_in[1];  // (1024,3072)
    const float* decay_bias = (const float*)d_in[2];  // (1024,)
    const float* W_mix      = (const float*)d_in[3];  // (1024,1024)
    const float* b_mix      = (const float*)d_in[4];  // (1024,)
    float* out = (float*)d_out;                       // (4,8192,1024) fp32

    // Workspace (~270 MB):
    //   aivh f16 [M_TOT,3072]            192 MB
    //   xh   f16 [M_TOT,1024]             64 MB  (reused as hb after GEMM1)
    //   ctd/cfs/incoming fp32 512K each    6 MB
    //   wT f16 [3072,1024], mT [1024,1024] 8 MB
    _Float16* aivh  = (_Float16*)d_ws;
    _Float16* xh    = aivh + (size_t)M_TOT * N_AIV;
    float* ctd      = (float*)(xh + (size_t)M_TOT * DREC);
    float* cfs      = ctd + (size_t)BATCH * NCHUNK * DREC;
    float* incoming = cfs + (size_t)BATCH * NCHUNK * DREC;
    _Float16* wT    = (_Float16*)(incoming + (size_t)BATCH * NCHUNK * DREC);
    _Float16* mT    = wT + (size_t)N_AIV * DREC;
    _Float16* hb    = xh;   // alias: xh dead after GEMM1

    // 0) conversions (x -> f16; weights -> transposed f16)
    cvt_to_f16<<<(M_TOT * DREC) / (256 * 8), 256, 0, stream>>>(x, xh);
    {
        dim3 g1(N_AIV / 32, DREC / 32);
        transpose_cvt<<<g1, 256, 0, stream>>>(W_aiv, DREC, N_AIV, wT);
        dim3 g2(DREC / 32, DREC / 32);
        transpose_cvt<<<g2, 256, 0, stream>>>(W_mix, DREC, DREC, mT);
    }
    // 1) aivh = xh @ W_aiv   (pure-f16 MFMA, f16 output)
    {
        dim3 grid(N_AIV / BN, M_TOT / BM);
        gemm_ff<true><<<grid, 256, 0, stream>>>(xh, DREC, wT, DREC,
                                                aivh, N_AIV, DREC, nullptr);
    }
    // 2) fused gates + intra scan -> chunk summaries
    scan_chunks<<<(BATCH * NCHUNK * 256) / 256, 256, 0, stream>>>(
        aivh, decay_bias, ctd, cfs);
    // 3) inter-chunk scan
    scan_inter<<<(BATCH * DREC) / 256, 256, 0, stream>>>(ctd, cfs, incoming);
    // 4) fused gates + intra scan + combine -> hb (f16, compact)
    scan_apply<<<(BATCH * NCHUNK * 256) / 256, 256, 0, stream>>>(
        aivh, decay_bias, incoming, hb);
    // 5) out = hb @ W_mix + b_mix  (pure-f16 MFMA, fp32 output)
    {
        dim3 grid(DREC / BN, M_TOT / BM);
        gemm_ff<false><<<grid, 256, 0, stream>>>(hb, DREC, mT, DREC,
                                                 out, DREC, DREC, b_mix);
    }
}